// Round 13
// baseline (66.809 us; speedup 1.0000x reference)
//
#include <hip/hip_runtime.h>

#define GAMMA 0.999f
#define LAMBD 0.7f
#define ALPHA 0.99f

constexpr int A_DIM = 64;
constexpr int CH    = 256;   // rows per block; nch = T/CH = 1024
constexpr int BLK   = 256;   // 4 waves; wave owns 64 main rows
constexpr int OVL   = 64;    // overlap rows (next chunk) for boundary value

typedef float fx4 __attribute__((ext_vector_type(4)));

__device__ __forceinline__ float dot4(const float4& a, const float4& b) {
    return a.x*b.x + a.y*b.y + a.z*b.z + a.w*b.w;
}
__device__ __forceinline__ void nt_store4(float* p, float x, float y, float z, float w) {
    fx4 v = { x, y, z, w };
    __builtin_nontemporal_store(v, (fx4*)p);
}

// ---------------------------------------------------------------------------
// Single kernel, no cross-block communication.
//  Decay: B_row = kmask*gamma*lambda*clip(rho) <= 0.6993 => 64-row suffix
//  product <= 1.1e-10. Block b computes its boundary value ye = y at chunk
//  end by redundantly composing the next chunk's first 64 rows' F (d2 dots +
//  gathers only), truncating beyond. Last block: ye = 0.
//  A: per-thread main-row gathers+scalars; tid<64 also overlap-row gathers;
//     16 lanes compute boundary dot d2[R0+CH].
//  B: software-pipelined same-row dots (pi,q,q_tar) for 256 main rows
//     (adv written NT) + 64 overlap d2 dots (pi,q_tar only).
//  C: 4-wave segmented suffix scan over main F; wave0 scans overlap F ->
//     sYe; all rows finalize targets = E + kmask*(Xa + Xb*ye).
// ---------------------------------------------------------------------------
__global__ __launch_bounds__(BLK, 4)
void k_main(const float* __restrict__ q, const float* __restrict__ q_tar,
            const float* __restrict__ pi, const int* __restrict__ a_t,
            const float* __restrict__ r_t, const float* __restrict__ mu_t,
            const int* __restrict__ done_t,
            float* __restrict__ adv_out, float* __restrict__ targets,
            int nch)
{
    __shared__ float sQa[CH], sPa[CH], sMa[CH], sKm[CH], sRt[CH];
    __shared__ float sV[CH], sVp[CH + 1];
    __shared__ float sQa2[OVL], sRho2[OVL], sKm2[OVL], sRt2[OVL];
    __shared__ float sVp2[OVL + 1];          // sVp2[j] = d2[R0+CH+j], j=1..64
    __shared__ float sCA[4], sCB[4];
    __shared__ float sYe;

    const int tid  = threadIdx.x;
    const int wave = tid >> 6, lane = tid & 63;
    const int sub  = lane >> 4, li = lane & 15;
    const int R0   = blockIdx.x * CH;
    const bool has_ovl = (blockIdx.x + 1 < nch);

    // ---- phase A: gathers + scalars
    {
        int r = R0 + tid;
        int a = a_t[r];
        sQa[tid] = q[r * A_DIM + a];
        sPa[tid] = pi[r * A_DIM + a];
        sMa[tid] = mu_t[r * A_DIM + a];
        sRt[tid] = r_t[r];
        sKm[tid] = 1.0f - (float)done_t[r];
    }
    if (tid < OVL && has_ovl) {              // overlap-row gathers
        int r = R0 + CH + tid;
        int a = a_t[r];
        sQa2[tid]  = q[r * A_DIM + a];
        sRho2[tid] = pi[r * A_DIM + a] / mu_t[r * A_DIM + a];
        sRt2[tid]  = r_t[r];
        sKm2[tid]  = 1.0f - (float)done_t[r];
    }
    if (tid >= 192 && tid < 208) {           // boundary dot d2[R0+CH] (row<=T)
        int l16 = tid - 192;
        int gE  = (R0 + CH) * A_DIM + l16 * 4;
        float4 pe = *(const float4*)&pi[gE];
        float4 qe = *(const float4*)&q_tar[gE];
        float d = dot4(pe, qe);
        #pragma unroll
        for (int off = 1; off < 16; off <<= 1) d += __shfl_xor(d, off);
        if (l16 == 0) sVp[CH] = d;
    }

    // ---- phase B: software-pipelined same-row dots + advantages (8 iters)
    const int lrow0 = wave * 64 + sub;
    float4 piA, qA, qtA, piB, qB, qtB;
    {
        int gA = (R0 + lrow0) * A_DIM + li * 4;
        int gB = gA + 4 * A_DIM;
        piA = *(const float4*)&pi[gA];
        qA  = *(const float4*)&q[gA];
        qtA = *(const float4*)&q_tar[gA];
        piB = *(const float4*)&pi[gB];
        qB  = *(const float4*)&q[gB];
        qtB = *(const float4*)&q_tar[gB];
    }
    #pragma unroll
    for (int i = 0; i < 8; ++i) {
        float4 npiA, nqA, nqtA, npiB, nqB, nqtB;
        if (i < 7) {
            int gA = (R0 + lrow0 + (i + 1) * 8) * A_DIM + li * 4;
            int gB = gA + 4 * A_DIM;
            npiA = *(const float4*)&pi[gA];
            nqA  = *(const float4*)&q[gA];
            nqtA = *(const float4*)&q_tar[gA];
            npiB = *(const float4*)&pi[gB];
            nqB  = *(const float4*)&q[gB];
            nqtB = *(const float4*)&q_tar[gB];
        }

        int lrowA = lrow0 + i * 8;
        int lrowB = lrowA + 4;
        int gA = (R0 + lrowA) * A_DIM + li * 4;
        int gB = (R0 + lrowB) * A_DIM + li * 4;

        float d1A = dot4(piA, qA),  d2A = dot4(piA, qtA);
        float d1B = dot4(piB, qB),  d2B = dot4(piB, qtB);
        #pragma unroll
        for (int off = 1; off < 16; off <<= 1) {
            d1A += __shfl_xor(d1A, off);
            d2A += __shfl_xor(d2A, off);
            d1B += __shfl_xor(d1B, off);
            d2B += __shfl_xor(d2B, off);
        }

        nt_store4(&adv_out[gA],
                  (1.0f - ALPHA) * (qA.x - d1A), (1.0f - ALPHA) * (qA.y - d1A),
                  (1.0f - ALPHA) * (qA.z - d1A), (1.0f - ALPHA) * (qA.w - d1A));
        nt_store4(&adv_out[gB],
                  (1.0f - ALPHA) * (qB.x - d1B), (1.0f - ALPHA) * (qB.y - d1B),
                  (1.0f - ALPHA) * (qB.z - d1B), (1.0f - ALPHA) * (qB.w - d1B));

        if (li == 0) {
            sV[lrowA] = d1A;  sVp[lrowA] = d2A;
            sV[lrowB] = d1B;  sVp[lrowB] = d2B;
        }

        piA = npiA; qA = nqA; qtA = nqtA;
        piB = npiB; qB = nqB; qtB = nqtB;
    }

    // ---- overlap d2 dots: rows R0+CH+1 .. R0+CH+64 (16 per wave, 2 iters)
    if (has_ovl) {
        #pragma unroll
        for (int i = 0; i < 2; ++i) {
            int j = wave * 16 + i * 8 + sub;          // 0..63
            int g = (R0 + CH + 1 + j) * A_DIM + li * 4;
            float4 pe = *(const float4*)&pi[g];
            float4 qe = *(const float4*)&q_tar[g];
            float d = dot4(pe, qe);
            #pragma unroll
            for (int off = 1; off < 16; off <<= 1) d += __shfl_xor(d, off);
            if (li == 0) sVp2[1 + j] = d;
        }
    }
    __syncthreads();

    // ---- phase C: main-row coefficients + 4-wave segmented suffix scan
    const int row = tid;
    float s0 = sV[row];
    float s1 = sVp[row + 1];
    float kmask = sKm[row];
    float qa  = sQa[row];
    float rho = sPa[row] / sMa[row];
    float est = sRt[row] + kmask * (GAMMA * s1);
    float td  = est - qa;
    float c   = LAMBD * fminf(fmaxf(rho, 0.0f), 1.0f);
    float Fa  = (LAMBD * GAMMA) * rho * td;   // y_t = Fa + Fb*y_{t+1}
    float Fb  = kmask * (GAMMA * c);
    float E   = est + ALPHA * (qa - s0);      // targets = E + kmask*y_{t+1}

    float Ai = Fa, Bi = Fb;                   // in-wave inclusive suffix scan
    #pragma unroll
    for (int off = 1; off < 64; off <<= 1) {
        float An = __shfl_down(Ai, off);
        float Bn = __shfl_down(Bi, off);
        if (lane + off < 64) { Ai += Bi * An; Bi *= Bn; }
    }
    if (lane == 0) { sCA[wave] = Ai; sCB[wave] = Bi; }
    float Xa = __shfl_down(Ai, 1);            // exclusive within segment
    float Xb = __shfl_down(Bi, 1);
    if (lane == 63) { Xa = 0.0f; Xb = 1.0f; }
    __syncthreads();

    // ---- overlap composite (wave 0): ye = comp(F2_0..F2_63) applied to 0
    if (wave == 0) {
        float Oa = 0.0f, Ob = 0.0f;
        if (has_ovl) {
            float km2  = sKm2[lane];
            float qa2  = sQa2[lane];
            float rho2 = sRho2[lane];
            float est2 = sRt2[lane] + km2 * (GAMMA * sVp2[lane + 1]);
            float td2  = est2 - qa2;
            float c2   = LAMBD * fminf(fmaxf(rho2, 0.0f), 1.0f);
            float Fa2  = (LAMBD * GAMMA) * rho2 * td2;
            float Fb2  = km2 * (GAMMA * c2);
            Oa = Fa2; Ob = Fb2;
            #pragma unroll
            for (int off = 1; off < 64; off <<= 1) {
                float An = __shfl_down(Oa, off);
                float Bn = __shfl_down(Ob, off);
                if (lane + off < 64) { Oa += Ob * An; Ob *= Bn; }
            }
        }
        if (lane == 0) sYe = Oa;             // truncate: y beyond 64 rows ~ 0
    }
    __syncthreads();

    // tail composite over segments wave+1..3, then append ye
    float Ta = 0.0f, Tb = 1.0f;
    for (int s = wave + 1; s < 4; ++s) {
        Ta += Tb * sCA[s];
        Tb *= sCB[s];
    }
    float ye = sYe;
    float y_next = Xa + Xb * (Ta + Tb * ye);  // y_{row+1}
    __builtin_nontemporal_store(E + kmask * y_next, &targets[R0 + row]);
}

extern "C" void kernel_launch(void* const* d_in, const int* in_sizes, int n_in,
                              void* d_out, int out_size, void* d_ws, size_t ws_size,
                              hipStream_t stream) {
    const float* q      = (const float*)d_in[0];
    const float* q_tar  = (const float*)d_in[1];
    const float* pi     = (const float*)d_in[2];
    const int*   a_t    = (const int*)  d_in[3];
    const float* r_t    = (const float*)d_in[4];
    const float* mu_t   = (const float*)d_in[5];
    const int*   done_t = (const int*)  d_in[6];

    const int T   = in_sizes[3];         // 262144
    const int nch = T / CH;              // 1024

    float* targets = (float*)d_out;          // T floats
    float* adv     = (float*)d_out + T;      // T*A floats

    k_main<<<nch, BLK, 0, stream>>>(q, q_tar, pi, a_t, r_t, mu_t, done_t,
                                    adv, targets, nch);
}

// Round 14
// 61.026 us; speedup vs baseline: 1.0948x; 1.0948x over previous
//
#include <hip/hip_runtime.h>

#define GAMMA 0.999f
#define LAMBD 0.7f
#define ALPHA 0.99f

constexpr int A_DIM = 64;
constexpr int CH    = 128;   // rows per block; nch = T/CH = 2048
constexpr int BLK   = 256;   // 4 waves; each wave computes 32 rows

typedef float fx4 __attribute__((ext_vector_type(4)));

__device__ __forceinline__ float dot4(const float4& a, const float4& b) {
    return a.x*b.x + a.y*b.y + a.z*b.z + a.w*b.w;
}
__device__ __forceinline__ void nt_store4(float* p, float x, float y, float z, float w) {
    fx4 v = { x, y, z, w };
    __builtin_nontemporal_store(v, (fx4*)p);
}
__device__ __forceinline__ float pick4(const float4& v, int k) {
    float lo = (k & 1) ? v.y : v.x;
    float hi = (k & 1) ? v.w : v.z;
    return (k & 2) ? hi : lo;
}

// ---------------------------------------------------------------------------
// K1 (R9 structure + in-stream action extraction):
//  A: scalars r_t/done (tid<128); mu-at-action gather only (tid>=128).
//  B: software-pipelined 4-stream dots (pi[r], q[r], pi[r+1], q_tar[r+1]);
//     per row, the lane holding chunk a>>2 extracts q_t_a / pi_t_a from the
//     streamed registers into LDS (deletes 2/3 of scattered gathers);
//     16-lane butterflies -> v_t, v_tp1; NT float4 advantages write.
//  C: waves 0,1: affine suffix scan via wave shuffles + cross-wave combine.
//     comb[t]={U,W}, cab[chunk]=composite.
// ---------------------------------------------------------------------------
__global__ __launch_bounds__(BLK, 4)
void k_main(const float* __restrict__ q, const float* __restrict__ q_tar,
            const float* __restrict__ pi, const int* __restrict__ a_t,
            const float* __restrict__ r_t, const float* __restrict__ mu_t,
            const int* __restrict__ done_t,
            float* __restrict__ adv_out,
            float2* __restrict__ comb, float2* __restrict__ cab)
{
    __shared__ float sQa[CH], sPa[CH], sMa[CH], sKm[CH], sRt[CH];
    __shared__ float sV[CH], sVp[CH];
    __shared__ float sWA[2], sWB[2];

    const int tid  = threadIdx.x;
    const int wave = tid >> 6, lane = tid & 63;
    const int sub  = lane >> 4, li = lane & 15;
    const int R0   = blockIdx.x * CH;

    // ---- phase A: scalars + mu-at-action gather only
    if (tid < CH) {
        int r = R0 + tid;
        sRt[tid] = r_t[r];
        sKm[tid] = 1.0f - (float)done_t[r];
    } else {
        int row = tid - CH;
        int r = R0 + row;
        int a = a_t[r];
        sMa[row] = mu_t[r * A_DIM + a];
    }

    // ---- phase B: software-pipelined dots + advantages + action extraction
    const int lrow0 = wave * 32 + sub;
    float4 piA, qA, pipA, qpA, piB, qB, pipB, qpB;
    {
        int gA = (R0 + lrow0) * A_DIM + li * 4;
        int gB = gA + 4 * A_DIM;
        piA  = *(const float4*)&pi[gA];
        qA   = *(const float4*)&q[gA];
        pipA = *(const float4*)&pi[gA + A_DIM];
        qpA  = *(const float4*)&q_tar[gA + A_DIM];
        piB  = *(const float4*)&pi[gB];
        qB   = *(const float4*)&q[gB];
        pipB = *(const float4*)&pi[gB + A_DIM];
        qpB  = *(const float4*)&q_tar[gB + A_DIM];
    }
    #pragma unroll
    for (int i = 0; i < 4; ++i) {
        float4 npiA, nqA, npipA, nqpA, npiB, nqB, npipB, nqpB;
        if (i < 3) {
            int gA = (R0 + lrow0 + (i + 1) * 8) * A_DIM + li * 4;
            int gB = gA + 4 * A_DIM;
            npiA  = *(const float4*)&pi[gA];
            nqA   = *(const float4*)&q[gA];
            npipA = *(const float4*)&pi[gA + A_DIM];
            nqpA  = *(const float4*)&q_tar[gA + A_DIM];
            npiB  = *(const float4*)&pi[gB];
            nqB   = *(const float4*)&q[gB];
            npipB = *(const float4*)&pi[gB + A_DIM];
            nqpB  = *(const float4*)&q_tar[gB + A_DIM];
        }

        int lrowA = lrow0 + i * 8;
        int lrowB = lrowA + 4;
        int gA = (R0 + lrowA) * A_DIM + li * 4;
        int gB = (R0 + lrowB) * A_DIM + li * 4;

        // in-stream extraction of q_t_a / pi_t_a (one lane per row)
        int aA = a_t[R0 + lrowA];
        int aB = a_t[R0 + lrowB];
        if (li == (aA >> 2)) {
            sQa[lrowA] = pick4(qA,  aA & 3);
            sPa[lrowA] = pick4(piA, aA & 3);
        }
        if (li == (aB >> 2)) {
            sQa[lrowB] = pick4(qB,  aB & 3);
            sPa[lrowB] = pick4(piB, aB & 3);
        }

        float s0A = dot4(piA, qA),  s1A = dot4(pipA, qpA);
        float s0B = dot4(piB, qB),  s1B = dot4(pipB, qpB);
        #pragma unroll
        for (int off = 1; off < 16; off <<= 1) {
            s0A += __shfl_xor(s0A, off);
            s1A += __shfl_xor(s1A, off);
            s0B += __shfl_xor(s0B, off);
            s1B += __shfl_xor(s1B, off);
        }

        nt_store4(&adv_out[gA],
                  (1.0f - ALPHA) * (qA.x - s0A), (1.0f - ALPHA) * (qA.y - s0A),
                  (1.0f - ALPHA) * (qA.z - s0A), (1.0f - ALPHA) * (qA.w - s0A));
        nt_store4(&adv_out[gB],
                  (1.0f - ALPHA) * (qB.x - s0B), (1.0f - ALPHA) * (qB.y - s0B),
                  (1.0f - ALPHA) * (qB.z - s0B), (1.0f - ALPHA) * (qB.w - s0B));

        if (li == 0) {
            sV[lrowA] = s0A;  sVp[lrowA] = s1A;
            sV[lrowB] = s0B;  sVp[lrowB] = s1B;
        }

        piA = npiA; qA = nqA; pipA = npipA; qpA = nqpA;
        piB = npiB; qB = nqB; pipB = npipB; qpB = nqpB;
    }
    __syncthreads();

    // ---- phase C: waves 0,1; lane owns row wave*64 + lane
    float Ai = 0.0f, Bi = 1.0f, Xa = 0.0f, Xb = 1.0f;
    float E = 0.0f, kmask = 0.0f;
    const int row = wave * 64 + lane;
    if (wave < 2) {
        float s0 = sV[row], s1 = sVp[row];
        kmask = sKm[row];
        float qa  = sQa[row];
        float rho = sPa[row] / sMa[row];
        float est = sRt[row] + kmask * (GAMMA * s1);
        float td  = est - qa;
        float c   = LAMBD * fminf(fmaxf(rho, 0.0f), 1.0f);
        float Fa  = (LAMBD * GAMMA) * rho * td;   // y_t = Fa + Fb*y_{t+1}
        float Fb  = kmask * (GAMMA * c);
        E = est + ALPHA * (qa - s0);              // targets = E + kmask*y_{t+1}

        Ai = Fa; Bi = Fb;                         // inclusive suffix scan
        #pragma unroll
        for (int off = 1; off < 64; off <<= 1) {
            float An = __shfl_down(Ai, off);
            float Bn = __shfl_down(Bi, off);
            if (lane + off < 64) { Ai += Bi * An; Bi *= Bn; }
        }
        if (lane == 0) { sWA[wave] = Ai; sWB[wave] = Bi; }
        Xa = __shfl_down(Ai, 1);                  // exclusive
        Xb = __shfl_down(Bi, 1);
        if (lane == 63) { Xa = 0.0f; Xb = 1.0f; }
    }
    __syncthreads();
    if (wave < 2) {
        if (wave == 0) {                          // append wave 1's composite
            Xa = Xa + Xb * sWA[1];
            Xb = Xb * sWB[1];
        }
        comb[R0 + row] = make_float2(E + kmask * Xa, kmask * Xb);
        if (tid == 0)
            cab[blockIdx.x] = make_float2(Ai + Bi * sWA[1], Bi * sWB[1]);
    }
}

// ---------------------------------------------------------------------------
// K2: each 128-thread block finalizes one 128-row chunk. Redundant suffix
// scan of nch=2048 chunk composites (16 KB, L2-hot): 16-chunk register fold
// per thread -> 128 supers -> wave scan + cross-wave combine; thread 0 folds
// the <=16-entry tail to get ye for this chunk.
// ---------------------------------------------------------------------------
__global__ __launch_bounds__(BLK / 2, 8)
void k_fin(const float2* __restrict__ comb, const float2* __restrict__ cab,
           float* __restrict__ targets, int nch)
{
    __shared__ float sXa[128], sXb[128];
    __shared__ float sWA[2], sWB[2];
    __shared__ float sYe;
    const int tid = threadIdx.x, bid = blockIdx.x;
    const int wave = tid >> 6, lane = tid & 63;

    // fold 16 consecutive chunks (8 float4 loads), outer-first order
    const float4* cab4 = (const float4*)cab;
    float A = 0.0f, B = 1.0f;
    #pragma unroll
    for (int j = 0; j < 8; ++j) {
        float4 u = cab4[tid * 8 + j];
        A += B * u.x; B *= u.y;
        A += B * u.z; B *= u.w;
    }

    // suffix scan over 128 supers: wave shuffle + cross-wave combine
    float Ai = A, Bi = B;
    #pragma unroll
    for (int off = 1; off < 64; off <<= 1) {
        float An = __shfl_down(Ai, off);
        float Bn = __shfl_down(Bi, off);
        if (lane + off < 64) { Ai += Bi * An; Bi *= Bn; }
    }
    if (lane == 0) { sWA[wave] = Ai; sWB[wave] = Bi; }
    float Xa = __shfl_down(Ai, 1);
    float Xb = __shfl_down(Bi, 1);
    if (lane == 63) { Xa = 0.0f; Xb = 1.0f; }
    __syncthreads();
    if (wave == 0) {
        Xa = Xa + Xb * sWA[1];
        Xb = Xb * sWB[1];
    }
    sXa[tid] = Xa; sXb[tid] = Xb;   // exclusive suffix over supers > tid
    __syncthreads();

    if (tid == 0) {
        int c1 = bid + 1;                  // suffix over chunks c1..nch-1
        float ye;
        if (c1 >= nch) {
            ye = 0.0f;
        } else {
            int jq = c1 >> 4;
            float Aa = sXa[jq], Bb = sXb[jq];     // suffix over supers > jq
            for (int k2 = 16 * jq + 15; k2 >= c1; --k2) {
                float2 cv = cab[k2];
                Aa = cv.x + cv.y * Aa;
                Bb = cv.y * Bb;
            }
            ye = Aa;
        }
        sYe = ye;
    }
    __syncthreads();

    float2 uw = comb[bid * CH + tid];
    __builtin_nontemporal_store(uw.x + uw.y * sYe, &targets[bid * CH + tid]);
}

extern "C" void kernel_launch(void* const* d_in, const int* in_sizes, int n_in,
                              void* d_out, int out_size, void* d_ws, size_t ws_size,
                              hipStream_t stream) {
    const float* q      = (const float*)d_in[0];
    const float* q_tar  = (const float*)d_in[1];
    const float* pi     = (const float*)d_in[2];
    const int*   a_t    = (const int*)  d_in[3];
    const float* r_t    = (const float*)d_in[4];
    const float* mu_t   = (const float*)d_in[5];
    const int*   done_t = (const int*)  d_in[6];

    const int T   = in_sizes[3];         // 262144
    const int nch = T / CH;              // 2048

    float* targets = (float*)d_out;          // T floats
    float* adv     = (float*)d_out + T;      // T*A floats

    char* ws = (char*)d_ws;
    float2* comb = (float2*)ws;              ws += (size_t)8 * T;
    float2* cab  = (float2*)ws;

    k_main<<<nch, BLK, 0, stream>>>(q, q_tar, pi, a_t, r_t, mu_t, done_t,
                                    adv, comb, cab);
    k_fin<<<nch, BLK / 2, 0, stream>>>(comb, cab, targets, nch);
}

// Round 15
// 59.994 us; speedup vs baseline: 1.1136x; 1.0172x over previous
//
#include <hip/hip_runtime.h>

#define GAMMA 0.999f
#define LAMBD 0.7f
#define ALPHA 0.99f

constexpr int A_DIM = 64;
constexpr int CH    = 128;   // rows per block; nch = T/CH = 2048
constexpr int BLK   = 256;   // 4 waves; each wave computes 32 rows

typedef float fx4 __attribute__((ext_vector_type(4)));

__device__ __forceinline__ float dot4(const float4& a, const float4& b) {
    return a.x*b.x + a.y*b.y + a.z*b.z + a.w*b.w;
}
__device__ __forceinline__ void nt_store4(float* p, float x, float y, float z, float w) {
    fx4 v = { x, y, z, w };
    __builtin_nontemporal_store(v, (fx4*)p);
}
__device__ __forceinline__ float pick4(const float4& v, int k) {
    float lo = (k & 1) ? v.y : v.x;
    float hi = (k & 1) ? v.w : v.z;
    return (k & 2) ? hi : lo;
}

// ---------------------------------------------------------------------------
// K1 (R14 extraction + R11 3-stream re-association):
//  d1[r] = pi[r]·q[r] (= v_t[r]); d2[r] = pi[r]·q_tar[r]; v_tp1[r] = d2[r+1].
//  Phase B loads only 3 SAME-ROW float4 streams (pi, q, q_tar); the lane
//  holding chunk a>>2 extracts q_t_a / pi_t_a from streamed registers.
//  A: scalars r_t/done (tid<128); mu-at-action gather (tid>=128); 16 lanes
//     (wave 2) compute boundary dot d2[R0+CH].
//  B: software-pipelined same-row dots; 16-lane butterflies -> d1, d2;
//     NT float4 advantages write; in-stream action extraction.
//  C: waves 0,1: s1 = sVp[row+1]; affine suffix scan via wave shuffles +
//     cross-wave combine. comb[t]={U,W}, cab[chunk]=composite.
// ---------------------------------------------------------------------------
__global__ __launch_bounds__(BLK, 4)
void k_main(const float* __restrict__ q, const float* __restrict__ q_tar,
            const float* __restrict__ pi, const int* __restrict__ a_t,
            const float* __restrict__ r_t, const float* __restrict__ mu_t,
            const int* __restrict__ done_t,
            float* __restrict__ adv_out,
            float2* __restrict__ comb, float2* __restrict__ cab)
{
    __shared__ float sQa[CH], sPa[CH], sMa[CH], sKm[CH], sRt[CH];
    __shared__ float sV[CH], sVp[CH + 1];
    __shared__ float sWA[2], sWB[2];

    const int tid  = threadIdx.x;
    const int wave = tid >> 6, lane = tid & 63;
    const int sub  = lane >> 4, li = lane & 15;
    const int R0   = blockIdx.x * CH;

    // ---- phase A: scalars + mu-at-action gather + boundary dot
    if (tid < CH) {
        int r = R0 + tid;
        sRt[tid] = r_t[r];
        sKm[tid] = 1.0f - (float)done_t[r];
    } else {
        int row = tid - CH;
        int r = R0 + row;
        int a = a_t[r];
        sMa[row] = mu_t[r * A_DIM + a];
    }
    if (tid >= 128 && tid < 144) {            // wave 2, lanes 0..15
        int l16 = tid - 128;
        int gE  = (R0 + CH) * A_DIM + l16 * 4;
        float4 pe = *(const float4*)&pi[gE];
        float4 qe = *(const float4*)&q_tar[gE];
        float d = dot4(pe, qe);
        #pragma unroll
        for (int off = 1; off < 16; off <<= 1) d += __shfl_xor(d, off);
        if (l16 == 0) sVp[CH] = d;
    }

    // ---- phase B: software-pipelined same-row dots + advantages + extraction
    const int lrow0 = wave * 32 + sub;
    float4 piA, qA, qtA, piB, qB, qtB;
    {
        int gA = (R0 + lrow0) * A_DIM + li * 4;
        int gB = gA + 4 * A_DIM;
        piA = *(const float4*)&pi[gA];
        qA  = *(const float4*)&q[gA];
        qtA = *(const float4*)&q_tar[gA];
        piB = *(const float4*)&pi[gB];
        qB  = *(const float4*)&q[gB];
        qtB = *(const float4*)&q_tar[gB];
    }
    #pragma unroll
    for (int i = 0; i < 4; ++i) {
        float4 npiA, nqA, nqtA, npiB, nqB, nqtB;
        if (i < 3) {
            int gA = (R0 + lrow0 + (i + 1) * 8) * A_DIM + li * 4;
            int gB = gA + 4 * A_DIM;
            npiA = *(const float4*)&pi[gA];
            nqA  = *(const float4*)&q[gA];
            nqtA = *(const float4*)&q_tar[gA];
            npiB = *(const float4*)&pi[gB];
            nqB  = *(const float4*)&q[gB];
            nqtB = *(const float4*)&q_tar[gB];
        }

        int lrowA = lrow0 + i * 8;
        int lrowB = lrowA + 4;
        int gA = (R0 + lrowA) * A_DIM + li * 4;
        int gB = (R0 + lrowB) * A_DIM + li * 4;

        // in-stream extraction of q_t_a / pi_t_a (one lane per row)
        int aA = a_t[R0 + lrowA];
        int aB = a_t[R0 + lrowB];
        if (li == (aA >> 2)) {
            sQa[lrowA] = pick4(qA,  aA & 3);
            sPa[lrowA] = pick4(piA, aA & 3);
        }
        if (li == (aB >> 2)) {
            sQa[lrowB] = pick4(qB,  aB & 3);
            sPa[lrowB] = pick4(piB, aB & 3);
        }

        float d1A = dot4(piA, qA),  d2A = dot4(piA, qtA);
        float d1B = dot4(piB, qB),  d2B = dot4(piB, qtB);
        #pragma unroll
        for (int off = 1; off < 16; off <<= 1) {
            d1A += __shfl_xor(d1A, off);
            d2A += __shfl_xor(d2A, off);
            d1B += __shfl_xor(d1B, off);
            d2B += __shfl_xor(d2B, off);
        }

        nt_store4(&adv_out[gA],
                  (1.0f - ALPHA) * (qA.x - d1A), (1.0f - ALPHA) * (qA.y - d1A),
                  (1.0f - ALPHA) * (qA.z - d1A), (1.0f - ALPHA) * (qA.w - d1A));
        nt_store4(&adv_out[gB],
                  (1.0f - ALPHA) * (qB.x - d1B), (1.0f - ALPHA) * (qB.y - d1B),
                  (1.0f - ALPHA) * (qB.z - d1B), (1.0f - ALPHA) * (qB.w - d1B));

        if (li == 0) {
            sV[lrowA] = d1A;  sVp[lrowA] = d2A;
            sV[lrowB] = d1B;  sVp[lrowB] = d2B;
        }

        piA = npiA; qA = nqA; qtA = nqtA;
        piB = npiB; qB = nqB; qtB = nqtB;
    }
    __syncthreads();

    // ---- phase C: waves 0,1; lane owns row wave*64 + lane
    float Ai = 0.0f, Bi = 1.0f, Xa = 0.0f, Xb = 1.0f;
    float E = 0.0f, kmask = 0.0f;
    const int row = wave * 64 + lane;
    if (wave < 2) {
        float s0 = sV[row];
        float s1 = sVp[row + 1];                  // v_tp1 = d2 of next row
        kmask = sKm[row];
        float qa  = sQa[row];
        float rho = sPa[row] / sMa[row];
        float est = sRt[row] + kmask * (GAMMA * s1);
        float td  = est - qa;
        float c   = LAMBD * fminf(fmaxf(rho, 0.0f), 1.0f);
        float Fa  = (LAMBD * GAMMA) * rho * td;   // y_t = Fa + Fb*y_{t+1}
        float Fb  = kmask * (GAMMA * c);
        E = est + ALPHA * (qa - s0);              // targets = E + kmask*y_{t+1}

        Ai = Fa; Bi = Fb;                         // inclusive suffix scan
        #pragma unroll
        for (int off = 1; off < 64; off <<= 1) {
            float An = __shfl_down(Ai, off);
            float Bn = __shfl_down(Bi, off);
            if (lane + off < 64) { Ai += Bi * An; Bi *= Bn; }
        }
        if (lane == 0) { sWA[wave] = Ai; sWB[wave] = Bi; }
        Xa = __shfl_down(Ai, 1);                  // exclusive
        Xb = __shfl_down(Bi, 1);
        if (lane == 63) { Xa = 0.0f; Xb = 1.0f; }
    }
    __syncthreads();
    if (wave < 2) {
        if (wave == 0) {                          // append wave 1's composite
            Xa = Xa + Xb * sWA[1];
            Xb = Xb * sWB[1];
        }
        comb[R0 + row] = make_float2(E + kmask * Xa, kmask * Xb);
        if (tid == 0)
            cab[blockIdx.x] = make_float2(Ai + Bi * sWA[1], Bi * sWB[1]);
    }
}

// ---------------------------------------------------------------------------
// K2: each 128-thread block finalizes one 128-row chunk. Redundant suffix
// scan of nch=2048 chunk composites (16 KB, L2-hot): 16-chunk register fold
// per thread -> 128 supers -> wave scan + cross-wave combine; thread 0 folds
// the <=16-entry tail to get ye for this chunk.
// ---------------------------------------------------------------------------
__global__ __launch_bounds__(BLK / 2, 8)
void k_fin(const float2* __restrict__ comb, const float2* __restrict__ cab,
           float* __restrict__ targets, int nch)
{
    __shared__ float sXa[128], sXb[128];
    __shared__ float sWA[2], sWB[2];
    __shared__ float sYe;
    const int tid = threadIdx.x, bid = blockIdx.x;
    const int wave = tid >> 6, lane = tid & 63;

    // fold 16 consecutive chunks (8 float4 loads), outer-first order
    const float4* cab4 = (const float4*)cab;
    float A = 0.0f, B = 1.0f;
    #pragma unroll
    for (int j = 0; j < 8; ++j) {
        float4 u = cab4[tid * 8 + j];
        A += B * u.x; B *= u.y;
        A += B * u.z; B *= u.w;
    }

    // suffix scan over 128 supers: wave shuffle + cross-wave combine
    float Ai = A, Bi = B;
    #pragma unroll
    for (int off = 1; off < 64; off <<= 1) {
        float An = __shfl_down(Ai, off);
        float Bn = __shfl_down(Bi, off);
        if (lane + off < 64) { Ai += Bi * An; Bi *= Bn; }
    }
    if (lane == 0) { sWA[wave] = Ai; sWB[wave] = Bi; }
    float Xa = __shfl_down(Ai, 1);
    float Xb = __shfl_down(Bi, 1);
    if (lane == 63) { Xa = 0.0f; Xb = 1.0f; }
    __syncthreads();
    if (wave == 0) {
        Xa = Xa + Xb * sWA[1];
        Xb = Xb * sWB[1];
    }
    sXa[tid] = Xa; sXb[tid] = Xb;   // exclusive suffix over supers > tid
    __syncthreads();

    if (tid == 0) {
        int c1 = bid + 1;                  // suffix over chunks c1..nch-1
        float ye;
        if (c1 >= nch) {
            ye = 0.0f;
        } else {
            int jq = c1 >> 4;
            float Aa = sXa[jq], Bb = sXb[jq];     // suffix over supers > jq
            for (int k2 = 16 * jq + 15; k2 >= c1; --k2) {
                float2 cv = cab[k2];
                Aa = cv.x + cv.y * Aa;
                Bb = cv.y * Bb;
            }
            ye = Aa;
        }
        sYe = ye;
    }
    __syncthreads();

    float2 uw = comb[bid * CH + tid];
    __builtin_nontemporal_store(uw.x + uw.y * sYe, &targets[bid * CH + tid]);
}

extern "C" void kernel_launch(void* const* d_in, const int* in_sizes, int n_in,
                              void* d_out, int out_size, void* d_ws, size_t ws_size,
                              hipStream_t stream) {
    const float* q      = (const float*)d_in[0];
    const float* q_tar  = (const float*)d_in[1];
    const float* pi     = (const float*)d_in[2];
    const int*   a_t    = (const int*)  d_in[3];
    const float* r_t    = (const float*)d_in[4];
    const float* mu_t   = (const float*)d_in[5];
    const int*   done_t = (const int*)  d_in[6];

    const int T   = in_sizes[3];         // 262144
    const int nch = T / CH;              // 2048

    float* targets = (float*)d_out;          // T floats
    float* adv     = (float*)d_out + T;      // T*A floats

    char* ws = (char*)d_ws;
    float2* comb = (float2*)ws;              ws += (size_t)8 * T;
    float2* cab  = (float2*)ws;

    k_main<<<nch, BLK, 0, stream>>>(q, q_tar, pi, a_t, r_t, mu_t, done_t,
                                    adv, comb, cab);
    k_fin<<<nch, BLK / 2, 0, stream>>>(comb, cab, targets, nch);
}